// Round 2
// baseline (650.728 us; speedup 1.0000x reference)
//
#include <hip/hip_runtime.h>

// GCN 2-layer: N=200000, E=12800000, features 2 -> 16 -> 2.
// R2: rank trick -- aggregate only 2-dim vectors (before W1 / after W2).
// R4: bucket counting-sort by dst (256-node buckets) + LDS-only aggregation.
// R5: scatter = block-local LDS counting sort + in-order coalesced copy-out.
// R6: agg/deg split into 4 segments/bucket with 4-way unrolled gather streams.
// R7: cache-policy + MLP fix. R6's agg ran 143.6 us at HBM 3.4% / VALU 1% --
//     the 12.8M random 8B gathers each pull a 64B line (819 MB effective) at
//     5.7 TB/s = L3-line-BW floor, because the concurrent 6.4MB/XCD `sorted`
//     stream evicts the 1.6MB table from L2. Fix: (a) non-temporal loads for
//     all streams (sorted/src/dst) + nt store for sorted, keeping the gather
//     table L2-resident; (b) consecutive-quad edge mapping: 4 edges/thread
//     via one dwordx4, 4-deep unrolled -> 16 gathers in flight per thread.
// R7b: __builtin_nontemporal_load rejects HIP_vector_type -- use a clang
//     ext_vector_type(4) alias instead (same global_load_dwordx4 nt).

constexpr int N_NODES = 200000;
constexpr int N_EDGES = 12800000;
constexpr int RANGE_SHIFT = 8;                       // 256 nodes / bucket
constexpr int K_BUCKETS = (N_NODES + 255) / 256;     // 782
constexpr int SORT_BLOCKS = 2048;
constexpr int CHUNK = N_EDGES / SORT_BLOCKS;         // 6250 exactly
constexpr int SCAN_R = SORT_BLOCKS / 256;            // 8
constexpr int SEG = 4;                               // segments per bucket

typedef unsigned uint32x4 __attribute__((ext_vector_type(4)));

// ---------------- sort phase ----------------

__global__ __launch_bounds__(256) void hist_kernel(const int* __restrict__ dst,
                                                   unsigned* __restrict__ blockHist) {
    __shared__ unsigned h[K_BUCKETS];
    for (int i = threadIdx.x; i < K_BUCKETS; i += 256) h[i] = 0;
    __syncthreads();
    int base = blockIdx.x * CHUNK;
    for (int e = base + threadIdx.x; e < base + CHUNK; e += 256)
        atomicAdd(&h[((unsigned)__builtin_nontemporal_load(&dst[e])) >> RANGE_SHIFT], 1u);
    __syncthreads();
    unsigned* row = blockHist + (size_t)blockIdx.x * K_BUCKETS;
    for (int i = threadIdx.x; i < K_BUCKETS; i += 256) row[i] = h[i];
}

// One block per bucket: exclusive scan over the SORT_BLOCKS per-block counts.
__global__ __launch_bounds__(256) void scan_perblock_kernel(unsigned* __restrict__ blockHist,
                                                            unsigned* __restrict__ bucketTotal) {
    int b = blockIdx.x, t = threadIdx.x;
    unsigned v[SCAN_R], run = 0;
#pragma unroll
    for (int j = 0; j < SCAN_R; j++) v[j] = blockHist[(size_t)(SCAN_R * t + j) * K_BUCKETS + b];
#pragma unroll
    for (int j = 0; j < SCAN_R; j++) { unsigned tmp = v[j]; v[j] = run; run += tmp; }
    __shared__ unsigned sh[256];
    sh[t] = run;
    __syncthreads();
    for (int off = 1; off < 256; off <<= 1) {
        unsigned add = (t >= off) ? sh[t - off] : 0u;
        __syncthreads();
        sh[t] += add;
        __syncthreads();
    }
    unsigned excl = sh[t] - run;
#pragma unroll
    for (int j = 0; j < SCAN_R; j++)
        blockHist[(size_t)(SCAN_R * t + j) * K_BUCKETS + b] = excl + v[j];
    if (t == 255) bucketTotal[b] = sh[255];
}

// Single block: exclusive scan of bucket totals -> bucketStart[0..K].
__global__ __launch_bounds__(1024) void scan_buckets_kernel(const unsigned* __restrict__ bucketTotal,
                                                            unsigned* __restrict__ bucketStart) {
    __shared__ unsigned sh[1024];
    int t = threadIdx.x;
    unsigned v = (t < K_BUCKETS) ? bucketTotal[t] : 0u;
    sh[t] = v;
    __syncthreads();
    for (int off = 1; off < 1024; off <<= 1) {
        unsigned add = (t >= off) ? sh[t - off] : 0u;
        __syncthreads();
        sh[t] += add;
        __syncthreads();
    }
    if (t < K_BUCKETS) bucketStart[t] = sh[t] - v;
    if (t == K_BUCKETS - 1) bucketStart[K_BUCKETS] = sh[t];
}

// Block-local counting sort in LDS, then in-order coalesced copy-out.
// Packed 4B entry: src (18b) | local_dst (8b) << 18.
__global__ __launch_bounds__(256) void scatter_kernel(const int* __restrict__ src,
                                                      const int* __restrict__ dst,
                                                      const unsigned* __restrict__ blockHist,
                                                      const unsigned* __restrict__ bucketStart,
                                                      unsigned* __restrict__ sorted) {
    __shared__ unsigned s_hist[K_BUCKETS];
    __shared__ unsigned s_cur[K_BUCKETS];
    __shared__ int      s_base[K_BUCKETS];
    __shared__ unsigned ssum[256];
    __shared__ unsigned ent[CHUNK];
    __shared__ unsigned short bk[CHUNK];

    int t = threadIdx.x;
    int base = blockIdx.x * CHUNK;
    for (int i = t; i < K_BUCKETS; i += 256) s_hist[i] = 0;
    __syncthreads();

    for (int e = base + t; e < base + CHUNK; e += 256)
        atomicAdd(&s_hist[((unsigned)__builtin_nontemporal_load(&dst[e])) >> RANGE_SHIFT], 1u);
    __syncthreads();

    unsigned v[4], run = 0;
#pragma unroll
    for (int j = 0; j < 4; j++) {
        int idx = 4 * t + j;
        v[j] = (idx < K_BUCKETS) ? s_hist[idx] : 0u;
    }
#pragma unroll
    for (int j = 0; j < 4; j++) { unsigned tmp = v[j]; v[j] = run; run += tmp; }
    ssum[t] = run;
    __syncthreads();
    for (int off = 1; off < 256; off <<= 1) {
        unsigned add = (t >= off) ? ssum[t - off] : 0u;
        __syncthreads();
        ssum[t] += add;
        __syncthreads();
    }
    unsigned excl = ssum[t] - run;
    const unsigned* row = blockHist + (size_t)blockIdx.x * K_BUCKETS;
#pragma unroll
    for (int j = 0; j < 4; j++) {
        int idx = 4 * t + j;
        if (idx < K_BUCKETS) {
            unsigned st = excl + v[j];
            s_cur[idx] = st;
            s_base[idx] = (int)(bucketStart[idx] + row[idx]) - (int)st;
        }
    }
    __syncthreads();

    for (int e = base + t; e < base + CHUNK; e += 256) {
        unsigned d = (unsigned)__builtin_nontemporal_load(&dst[e]);
        unsigned s = (unsigned)__builtin_nontemporal_load(&src[e]);
        unsigned b = d >> RANGE_SHIFT;
        unsigned lpos = atomicAdd(&s_cur[b], 1u);
        ent[lpos] = s | ((d & 255u) << 18);
        bk[lpos] = (unsigned short)b;
    }
    __syncthreads();

    for (int i = t; i < CHUNK; i += 256) {
        unsigned b = bk[i];
        __builtin_nontemporal_store(ent[i], &sorted[s_base[b] + i]);
    }
}

// ---------------- GCN phase ----------------
// Grids of K_BUCKETS*SEG blocks: b = blockIdx.x>>2, s = blockIdx.x&3.
// Edge ranges are processed as 16B-aligned quads (dwordx4 nt loads) with
// scalar head/tail; 4-deep unroll puts 16 random gathers in flight/thread.

__device__ __forceinline__ void seg_bounds(const unsigned* __restrict__ bucketStart,
                                           int bid, int& e0, int& e1) {
    int b = bid >> 2, s = bid & 3;
    int s0 = bucketStart[b], len = bucketStart[b + 1] - s0;
    e0 = s0 + (len * s) / SEG;
    e1 = s0 + (len * (s + 1)) / SEG;
}

__global__ __launch_bounds__(256) void deg_part_kernel(const unsigned* __restrict__ sorted,
                                                       const unsigned* __restrict__ bucketStart,
                                                       unsigned* __restrict__ pcnt) {
    __shared__ unsigned cnt[256];
    int t = threadIdx.x;
    cnt[t] = 0;
    __syncthreads();
    int e0, e1;
    seg_bounds(bucketStart, blockIdx.x, e0, e1);

    int e0a = (e0 + 3) & ~3;
    if (e0a > e1) e0a = e1;
    if (t < e0a - e0) {
        unsigned w = __builtin_nontemporal_load(&sorted[e0 + t]);
        atomicAdd(&cnt[(w >> 18) & 255u], 1u);
    }
    int nq = (e1 - e0a) >> 2;
    const uint32x4* q4 = (const uint32x4*)(sorted + e0a);
    int q = t;
    for (; q + 768 < nq; q += 1024) {
        uint32x4 w0 = __builtin_nontemporal_load(&q4[q]);
        uint32x4 w1 = __builtin_nontemporal_load(&q4[q + 256]);
        uint32x4 w2 = __builtin_nontemporal_load(&q4[q + 512]);
        uint32x4 w3 = __builtin_nontemporal_load(&q4[q + 768]);
#pragma unroll
        for (int j = 0; j < 4; j++) atomicAdd(&cnt[(w0[j] >> 18) & 255u], 1u);
#pragma unroll
        for (int j = 0; j < 4; j++) atomicAdd(&cnt[(w1[j] >> 18) & 255u], 1u);
#pragma unroll
        for (int j = 0; j < 4; j++) atomicAdd(&cnt[(w2[j] >> 18) & 255u], 1u);
#pragma unroll
        for (int j = 0; j < 4; j++) atomicAdd(&cnt[(w3[j] >> 18) & 255u], 1u);
    }
    for (; q < nq; q += 256) {
        uint32x4 w0 = __builtin_nontemporal_load(&q4[q]);
#pragma unroll
        for (int j = 0; j < 4; j++) atomicAdd(&cnt[(w0[j] >> 18) & 255u], 1u);
    }
    int tail0 = e0a + (nq << 2);
    if (t < e1 - tail0) {
        unsigned w = __builtin_nontemporal_load(&sorted[tail0 + t]);
        atomicAdd(&cnt[(w >> 18) & 255u], 1u);
    }
    __syncthreads();
    pcnt[(size_t)blockIdx.x * 256 + t] = cnt[t];
}

__global__ __launch_bounds__(256) void node1_kernel(const float2* __restrict__ x,
                                                    const unsigned* __restrict__ pcnt,
                                                    float* __restrict__ dinv,
                                                    float2* __restrict__ u) {
    int i = blockIdx.x * 256 + threadIdx.x;
    if (i >= N_NODES) return;
    int b = i >> 8, l = i & 255;
    unsigned c = 1;  // +1 self loop
#pragma unroll
    for (int s = 0; s < SEG; s++) c += pcnt[(size_t)(b * SEG + s) * 256 + l];
    float di = rsqrtf((float)c);
    dinv[i] = di;
    float2 xi = x[i];
    u[i] = make_float2(di * xi.x, di * xi.y);
}

__device__ __forceinline__ void agg_gather(const float2* __restrict__ table,
                                           const uint32x4 w, float2 v[4]) {
    v[0] = table[w[0] & 0x3FFFFu];
    v[1] = table[w[1] & 0x3FFFFu];
    v[2] = table[w[2] & 0x3FFFFu];
    v[3] = table[w[3] & 0x3FFFFu];
}

__device__ __forceinline__ void agg_accum(float* ax, float* ay,
                                          const uint32x4 w, const float2 v[4]) {
#pragma unroll
    for (int j = 0; j < 4; j++) {
        unsigned l = (w[j] >> 18) & 255u;
        atomicAdd(&ax[l], v[j].x);
        atomicAdd(&ay[l], v[j].y);
    }
}

// Partial aggregation: gather table[src] for one bucket-segment, LDS-sum,
// write a float2[256] partial.
__global__ __launch_bounds__(256) void agg_part_kernel(const unsigned* __restrict__ sorted,
                                                       const unsigned* __restrict__ bucketStart,
                                                       const float2* __restrict__ table,
                                                       float2* __restrict__ part) {
    __shared__ float ax[256], ay[256];
    int t = threadIdx.x;
    ax[t] = 0.f; ay[t] = 0.f;
    __syncthreads();
    int e0, e1;
    seg_bounds(bucketStart, blockIdx.x, e0, e1);

    int e0a = (e0 + 3) & ~3;
    if (e0a > e1) e0a = e1;
    if (t < e0a - e0) {
        unsigned w = __builtin_nontemporal_load(&sorted[e0 + t]);
        float2 v = table[w & 0x3FFFFu];
        unsigned l = (w >> 18) & 255u;
        atomicAdd(&ax[l], v.x);
        atomicAdd(&ay[l], v.y);
    }
    int nq = (e1 - e0a) >> 2;
    const uint32x4* q4 = (const uint32x4*)(sorted + e0a);
    int q = t;
    for (; q + 768 < nq; q += 1024) {
        uint32x4 w0 = __builtin_nontemporal_load(&q4[q]);
        uint32x4 w1 = __builtin_nontemporal_load(&q4[q + 256]);
        uint32x4 w2 = __builtin_nontemporal_load(&q4[q + 512]);
        uint32x4 w3 = __builtin_nontemporal_load(&q4[q + 768]);
        float2 v0[4], v1[4], v2[4], v3[4];
        agg_gather(table, w0, v0);
        agg_gather(table, w1, v1);
        agg_gather(table, w2, v2);
        agg_gather(table, w3, v3);
        agg_accum(ax, ay, w0, v0);
        agg_accum(ax, ay, w1, v1);
        agg_accum(ax, ay, w2, v2);
        agg_accum(ax, ay, w3, v3);
    }
    for (; q < nq; q += 256) {
        uint32x4 w0 = __builtin_nontemporal_load(&q4[q]);
        float2 v0[4];
        agg_gather(table, w0, v0);
        agg_accum(ax, ay, w0, v0);
    }
    int tail0 = e0a + (nq << 2);
    if (t < e1 - tail0) {
        unsigned w = __builtin_nontemporal_load(&sorted[tail0 + t]);
        float2 v = table[w & 0x3FFFFu];
        unsigned l = (w >> 18) & 255u;
        atomicAdd(&ax[l], v.x);
        atomicAdd(&ay[l], v.y);
    }
    __syncthreads();
    part[(size_t)blockIdx.x * 256 + t] = make_float2(ax[t], ay[t]);
}

__global__ __launch_bounds__(256) void node2_kernel(const float2* __restrict__ u,
                                                    const float2* __restrict__ part,
                                                    const float* __restrict__ W1,
                                                    const float* __restrict__ b1,
                                                    const float* __restrict__ W2,
                                                    const float* __restrict__ dinv,
                                                    float2* __restrict__ g2) {
    int i = blockIdx.x * 256 + threadIdx.x;
    if (i >= N_NODES) return;
    int b = i >> 8, l = i & 255;
    float ax = 0.f, ay = 0.f;
#pragma unroll
    for (int s = 0; s < SEG; s++) {
        float2 p = part[(size_t)(b * SEG + s) * 256 + l];
        ax += p.x; ay += p.y;
    }
    float di = dinv[i];
    float2 uu = u[i];
    float c0 = di * (ax + uu.x);
    float c1 = di * (ay + uu.y);
    float a0 = 0.f, a1 = 0.f;
#pragma unroll
    for (int f = 0; f < 16; f++) {
        float o = fmaxf(c0 * W1[f] + c1 * W1[16 + f] + b1[f], 0.f);  // W1 (2,16)
        a0 += o * W2[2 * f];                                         // W2 (16,2)
        a1 += o * W2[2 * f + 1];
    }
    g2[i] = make_float2(di * a0, di * a1);
}

__global__ __launch_bounds__(256) void node3_kernel(const float2* __restrict__ g2,
                                                    const float2* __restrict__ part,
                                                    const float* __restrict__ b2,
                                                    const float* __restrict__ dinv,
                                                    float2* __restrict__ out) {
    int i = blockIdx.x * 256 + threadIdx.x;
    if (i >= N_NODES) return;
    int b = i >> 8, l = i & 255;
    float ax = 0.f, ay = 0.f;
#pragma unroll
    for (int s = 0; s < SEG; s++) {
        float2 p = part[(size_t)(b * SEG + s) * 256 + l];
        ax += p.x; ay += p.y;
    }
    float di = dinv[i];
    float2 g = g2[i];
    out[i] = make_float2(di * (ax + g.x) + b2[0],
                         di * (ay + g.y) + b2[1]);
}

// ---------------- fallback path (R2-style, needs only 8 MB ws) ----------------

__global__ __launch_bounds__(256) void fb_deg(const int* __restrict__ dst, int* __restrict__ degi) {
    int e = blockIdx.x * 256 + threadIdx.x;
    if (e < N_EDGES) atomicAdd(&degi[dst[e]], 1);
}
__global__ __launch_bounds__(256) void fb_node1(const float* __restrict__ x, const int* __restrict__ degi,
                                                float* __restrict__ dinv, float2* __restrict__ u) {
    int i = blockIdx.x * 256 + threadIdx.x;
    if (i >= N_NODES) return;
    float di = rsqrtf((float)(degi[i] + 1));
    dinv[i] = di;
    float2 xi = ((const float2*)x)[i];
    u[i] = make_float2(di * xi.x, di * xi.y);
}
__global__ __launch_bounds__(256) void fb_agg(const int* __restrict__ src, const int* __restrict__ dst,
                                              const float2* __restrict__ table, float* __restrict__ acc) {
    int e = blockIdx.x * 256 + threadIdx.x;
    if (e >= N_EDGES) return;
    float2 v = table[src[e]];
    size_t d = dst[e];
    unsafeAtomicAdd(&acc[2 * d], v.x);
    unsafeAtomicAdd(&acc[2 * d + 1], v.y);
}
__global__ __launch_bounds__(256) void fb_node2(const float2* __restrict__ u, const float2* __restrict__ A1,
                                                const float* __restrict__ W1, const float* __restrict__ b1,
                                                const float* __restrict__ W2, const float* __restrict__ dinv,
                                                float2* __restrict__ g2) {
    int i = blockIdx.x * 256 + threadIdx.x;
    if (i >= N_NODES) return;
    float di = dinv[i];
    float2 a = A1[i], uu = u[i];
    float c0 = di * (a.x + uu.x), c1 = di * (a.y + uu.y);
    float a0 = 0.f, a1 = 0.f;
#pragma unroll
    for (int f = 0; f < 16; f++) {
        float o = fmaxf(c0 * W1[f] + c1 * W1[16 + f] + b1[f], 0.f);
        a0 += o * W2[2 * f];
        a1 += o * W2[2 * f + 1];
    }
    g2[i] = make_float2(di * a0, di * a1);
}
__global__ __launch_bounds__(256) void fb_node3(const float2* __restrict__ g2, const float2* __restrict__ A2,
                                                const float* __restrict__ b2, const float* __restrict__ dinv,
                                                float2* __restrict__ out) {
    int i = blockIdx.x * 256 + threadIdx.x;
    if (i >= N_NODES) return;
    float di = dinv[i];
    float2 a = A2[i], g = g2[i];
    out[i] = make_float2(di * (a.x + g.x) + b2[0], di * (a.y + g.y) + b2[1]);
}

// ---------------- launcher ----------------

extern "C" void kernel_launch(void* const* d_in, const int* in_sizes, int n_in,
                              void* d_out, int out_size, void* d_ws, size_t ws_size,
                              hipStream_t stream) {
    const float* x  = (const float*)d_in[0];
    const float* W1 = (const float*)d_in[1];
    const float* b1 = (const float*)d_in[2];
    const float* W2 = (const float*)d_in[3];
    const float* b2 = (const float*)d_in[4];
    const int* ei   = (const int*)d_in[5];   // (2,E): row 0 = src, row 1 = dst
    const int* src = ei;
    const int* dst = ei + N_EDGES;
    float2* out = (float2*)d_out;

    // ws layout (4B words), same total as R5 (~61.6 MB):
    //   sorted      [E]                      12,800,000
    //   blockHist   [SORT_BLOCKS*K]           1,601,536  -- dead after scatter;
    //       reused for deg partials (3128*256 = 800,768 words) and
    //       agg partials (3128*512 = 1,601,536 words -- exact fit)
    //   bucketTotal [K]                             782
    //   bucketStart [K+1] (+1 pad)                  784
    //   dinv        [N]                         200,000
    //   u           [2N] (8B aligned)           400,000
    //   g2          [2N]                        400,000
    const size_t need = ((size_t)N_EDGES + (size_t)SORT_BLOCKS * K_BUCKETS + 782 + 784
                         + N_NODES + 2 * (size_t)N_NODES + 2 * (size_t)N_NODES) * 4;

    if (ws_size >= need) {
        unsigned* sorted      = (unsigned*)d_ws;
        unsigned* blockHist   = sorted + N_EDGES;
        unsigned* bucketTotal = blockHist + (size_t)SORT_BLOCKS * K_BUCKETS;
        unsigned* bucketStart = bucketTotal + 782;
        float*    dinv        = (float*)(bucketStart + 784);
        float2*   u           = (float2*)(dinv + N_NODES);
        float2*   g2          = u + N_NODES;
        unsigned* pcnt        = blockHist;            // deg partials (reuse)
        float2*   part        = (float2*)blockHist;   // agg partials (reuse)

        hist_kernel<<<SORT_BLOCKS, 256, 0, stream>>>(dst, blockHist);
        scan_perblock_kernel<<<K_BUCKETS, 256, 0, stream>>>(blockHist, bucketTotal);
        scan_buckets_kernel<<<1, 1024, 0, stream>>>(bucketTotal, bucketStart);
        scatter_kernel<<<SORT_BLOCKS, 256, 0, stream>>>(src, dst, blockHist, bucketStart, sorted);
        deg_part_kernel<<<K_BUCKETS * SEG, 256, 0, stream>>>(sorted, bucketStart, pcnt);
        node1_kernel<<<K_BUCKETS, 256, 0, stream>>>((const float2*)x, pcnt, dinv, u);
        agg_part_kernel<<<K_BUCKETS * SEG, 256, 0, stream>>>(sorted, bucketStart, u, part);
        node2_kernel<<<K_BUCKETS, 256, 0, stream>>>(u, part, W1, b1, W2, dinv, g2);
        agg_part_kernel<<<K_BUCKETS * SEG, 256, 0, stream>>>(sorted, bucketStart, g2, part);
        node3_kernel<<<K_BUCKETS, 256, 0, stream>>>(g2, part, b2, dinv, out);
    } else {
        // R2-style fallback (8 MB ws): global atomics, ~3.1 ms.
        float* ws = (float*)d_ws;
        int*   degi = (int*)ws;
        float* A1   = ws + N_NODES;
        float* A2   = A1 + 2 * (size_t)N_NODES;
        float* dinvF = A2 + 2 * (size_t)N_NODES;
        float2* uF  = (float2*)(dinvF + N_NODES);
        float2* g2F = uF + N_NODES;
        constexpr int EB = (N_EDGES + 255) / 256;
        constexpr int NB = (N_NODES + 255) / 256;
        (void)hipMemsetAsync(degi, 0, 5 * (size_t)N_NODES * sizeof(float), stream);
        fb_deg<<<EB, 256, 0, stream>>>(dst, degi);
        fb_node1<<<NB, 256, 0, stream>>>(x, degi, dinvF, uF);
        fb_agg<<<EB, 256, 0, stream>>>(src, dst, uF, A1);
        fb_node2<<<NB, 256, 0, stream>>>(uF, (const float2*)A1, W1, b1, W2, dinvF, g2F);
        fb_agg<<<EB, 256, 0, stream>>>(src, dst, g2F, A2);
        fb_node3<<<NB, 256, 0, stream>>>(g2F, (const float2*)A2, b2, dinvF, out);
    }
}

// Round 3
// 586.263 us; speedup vs baseline: 1.1100x; 1.1100x over previous
//
#include <hip/hip_runtime.h>

// GCN 2-layer: N=200000, E=12800000, features 2 -> 16 -> 2.
// R2: rank trick -- aggregate only 2-dim vectors (before W1 / after W2).
// R4: bucket counting-sort by dst (256-node buckets) + LDS-only aggregation.
// R5: scatter = block-local LDS counting sort + in-order coalesced copy-out.
// R6: agg/deg split into 4 segments/bucket with 4-way unrolled gather streams.
// R7 (FAILED): nt loads/stores everywhere. nt 4B stores in scatter bypass L2
//     write-merge -> WRITE_SIZE 97.7MB (1.9x ideal), scatter 154us. Agg was
//     unchanged: gathers are THROUGHPUT-saturated (~7 cyc per divergent lane
//     per CU in the TA/L1 miss path), not latency-bound -- 16-deep MLP gave 0.
// R8: revert all nt. Scatter no longer re-histograms: per-block bucket counts
//     are reconstructed as blockHist[k+1][b]-blockHist[k][b] (last block uses
//     bucketTotal), dropping a 51.2MB dst pass + 12.8M LDS atomics from the
//     hottest sort kernel. deg/agg keep the quad-load form with cached loads.

constexpr int N_NODES = 200000;
constexpr int N_EDGES = 12800000;
constexpr int RANGE_SHIFT = 8;                       // 256 nodes / bucket
constexpr int K_BUCKETS = (N_NODES + 255) / 256;     // 782
constexpr int SORT_BLOCKS = 2048;
constexpr int CHUNK = N_EDGES / SORT_BLOCKS;         // 6250 exactly
constexpr int SCAN_R = SORT_BLOCKS / 256;            // 8
constexpr int SEG = 4;                               // segments per bucket

typedef unsigned uint32x4 __attribute__((ext_vector_type(4)));

// ---------------- sort phase ----------------

__global__ __launch_bounds__(256) void hist_kernel(const int* __restrict__ dst,
                                                   unsigned* __restrict__ blockHist) {
    __shared__ unsigned h[K_BUCKETS];
    for (int i = threadIdx.x; i < K_BUCKETS; i += 256) h[i] = 0;
    __syncthreads();
    int base = blockIdx.x * CHUNK;
    for (int e = base + threadIdx.x; e < base + CHUNK; e += 256)
        atomicAdd(&h[((unsigned)dst[e]) >> RANGE_SHIFT], 1u);
    __syncthreads();
    unsigned* row = blockHist + (size_t)blockIdx.x * K_BUCKETS;
    for (int i = threadIdx.x; i < K_BUCKETS; i += 256) row[i] = h[i];
}

// One block per bucket: exclusive scan over the SORT_BLOCKS per-block counts.
__global__ __launch_bounds__(256) void scan_perblock_kernel(unsigned* __restrict__ blockHist,
                                                            unsigned* __restrict__ bucketTotal) {
    int b = blockIdx.x, t = threadIdx.x;
    unsigned v[SCAN_R], run = 0;
#pragma unroll
    for (int j = 0; j < SCAN_R; j++) v[j] = blockHist[(size_t)(SCAN_R * t + j) * K_BUCKETS + b];
#pragma unroll
    for (int j = 0; j < SCAN_R; j++) { unsigned tmp = v[j]; v[j] = run; run += tmp; }
    __shared__ unsigned sh[256];
    sh[t] = run;
    __syncthreads();
    for (int off = 1; off < 256; off <<= 1) {
        unsigned add = (t >= off) ? sh[t - off] : 0u;
        __syncthreads();
        sh[t] += add;
        __syncthreads();
    }
    unsigned excl = sh[t] - run;
#pragma unroll
    for (int j = 0; j < SCAN_R; j++)
        blockHist[(size_t)(SCAN_R * t + j) * K_BUCKETS + b] = excl + v[j];
    if (t == 255) bucketTotal[b] = sh[255];
}

// Single block: exclusive scan of bucket totals -> bucketStart[0..K].
__global__ __launch_bounds__(1024) void scan_buckets_kernel(const unsigned* __restrict__ bucketTotal,
                                                            unsigned* __restrict__ bucketStart) {
    __shared__ unsigned sh[1024];
    int t = threadIdx.x;
    unsigned v = (t < K_BUCKETS) ? bucketTotal[t] : 0u;
    sh[t] = v;
    __syncthreads();
    for (int off = 1; off < 1024; off <<= 1) {
        unsigned add = (t >= off) ? sh[t - off] : 0u;
        __syncthreads();
        sh[t] += add;
        __syncthreads();
    }
    if (t < K_BUCKETS) bucketStart[t] = sh[t] - v;
    if (t == K_BUCKETS - 1) bucketStart[K_BUCKETS] = sh[t];
}

// Block-local counting sort in LDS, then in-order coalesced copy-out.
// Packed 4B entry: src (18b) | local_dst (8b) << 18.
// R8: local bucket counts come from blockHist[k+1]-blockHist[k] (scanned
// offsets), NOT from a re-histogram pass over dst.
__global__ __launch_bounds__(256) void scatter_kernel(const int* __restrict__ src,
                                                      const int* __restrict__ dst,
                                                      const unsigned* __restrict__ blockHist,
                                                      const unsigned* __restrict__ bucketTotal,
                                                      const unsigned* __restrict__ bucketStart,
                                                      unsigned* __restrict__ sorted) {
    __shared__ unsigned s_cur[K_BUCKETS];
    __shared__ int      s_base[K_BUCKETS];
    __shared__ unsigned ssum[256];
    __shared__ unsigned ent[CHUNK];
    __shared__ unsigned short bk[CHUNK];

    int t = threadIdx.x;
    int k = blockIdx.x;
    int base = k * CHUNK;
    const unsigned* row  = blockHist + (size_t)k * K_BUCKETS;
    const unsigned* rowN = blockHist + (size_t)(k + 1) * K_BUCKETS;
    bool last = (k == SORT_BLOCKS - 1);

    unsigned v[4], g0[4], run = 0;
#pragma unroll
    for (int j = 0; j < 4; j++) {
        int idx = 4 * t + j;
        if (idx < K_BUCKETS) {
            unsigned r0 = row[idx];
            unsigned r1 = last ? bucketTotal[idx] : rowN[idx];
            g0[j] = r0;
            v[j]  = r1 - r0;          // this block's count for bucket idx
        } else { g0[j] = 0; v[j] = 0; }
    }
#pragma unroll
    for (int j = 0; j < 4; j++) { unsigned tmp = v[j]; v[j] = run; run += tmp; }
    ssum[t] = run;
    __syncthreads();
    for (int off = 1; off < 256; off <<= 1) {
        unsigned add = (t >= off) ? ssum[t - off] : 0u;
        __syncthreads();
        ssum[t] += add;
        __syncthreads();
    }
    unsigned excl = ssum[t] - run;
#pragma unroll
    for (int j = 0; j < 4; j++) {
        int idx = 4 * t + j;
        if (idx < K_BUCKETS) {
            unsigned st = excl + v[j];          // local start of bucket idx
            s_cur[idx]  = st;
            s_base[idx] = (int)(bucketStart[idx] + g0[j]) - (int)st;
        }
    }
    __syncthreads();

    for (int e = base + t; e < base + CHUNK; e += 256) {
        unsigned d = (unsigned)dst[e];
        unsigned s = (unsigned)src[e];
        unsigned b = d >> RANGE_SHIFT;
        unsigned lpos = atomicAdd(&s_cur[b], 1u);
        ent[lpos] = s | ((d & 255u) << 18);
        bk[lpos] = (unsigned short)b;
    }
    __syncthreads();

    for (int i = t; i < CHUNK; i += 256) {
        unsigned b = bk[i];
        sorted[s_base[b] + i] = ent[i];
    }
}

// ---------------- GCN phase ----------------
// Grids of K_BUCKETS*SEG blocks: b = blockIdx.x>>2, s = blockIdx.x&3.
// Edge ranges processed as 16B-aligned quads (dwordx4 cached loads) with
// scalar head/tail; 4-deep unroll -> 16 gathers in flight per thread.

__device__ __forceinline__ void seg_bounds(const unsigned* __restrict__ bucketStart,
                                           int bid, int& e0, int& e1) {
    int b = bid >> 2, s = bid & 3;
    int s0 = bucketStart[b], len = bucketStart[b + 1] - s0;
    e0 = s0 + (len * s) / SEG;
    e1 = s0 + (len * (s + 1)) / SEG;
}

__global__ __launch_bounds__(256) void deg_part_kernel(const unsigned* __restrict__ sorted,
                                                       const unsigned* __restrict__ bucketStart,
                                                       unsigned* __restrict__ pcnt) {
    __shared__ unsigned cnt[256];
    int t = threadIdx.x;
    cnt[t] = 0;
    __syncthreads();
    int e0, e1;
    seg_bounds(bucketStart, blockIdx.x, e0, e1);

    int e0a = (e0 + 3) & ~3;
    if (e0a > e1) e0a = e1;
    if (t < e0a - e0) {
        unsigned w = sorted[e0 + t];
        atomicAdd(&cnt[(w >> 18) & 255u], 1u);
    }
    int nq = (e1 - e0a) >> 2;
    const uint32x4* q4 = (const uint32x4*)(sorted + e0a);
    int q = t;
    for (; q + 768 < nq; q += 1024) {
        uint32x4 w0 = q4[q];
        uint32x4 w1 = q4[q + 256];
        uint32x4 w2 = q4[q + 512];
        uint32x4 w3 = q4[q + 768];
#pragma unroll
        for (int j = 0; j < 4; j++) atomicAdd(&cnt[(w0[j] >> 18) & 255u], 1u);
#pragma unroll
        for (int j = 0; j < 4; j++) atomicAdd(&cnt[(w1[j] >> 18) & 255u], 1u);
#pragma unroll
        for (int j = 0; j < 4; j++) atomicAdd(&cnt[(w2[j] >> 18) & 255u], 1u);
#pragma unroll
        for (int j = 0; j < 4; j++) atomicAdd(&cnt[(w3[j] >> 18) & 255u], 1u);
    }
    for (; q < nq; q += 256) {
        uint32x4 w0 = q4[q];
#pragma unroll
        for (int j = 0; j < 4; j++) atomicAdd(&cnt[(w0[j] >> 18) & 255u], 1u);
    }
    int tail0 = e0a + (nq << 2);
    if (t < e1 - tail0) {
        unsigned w = sorted[tail0 + t];
        atomicAdd(&cnt[(w >> 18) & 255u], 1u);
    }
    __syncthreads();
    pcnt[(size_t)blockIdx.x * 256 + t] = cnt[t];
}

__global__ __launch_bounds__(256) void node1_kernel(const float2* __restrict__ x,
                                                    const unsigned* __restrict__ pcnt,
                                                    float* __restrict__ dinv,
                                                    float2* __restrict__ u) {
    int i = blockIdx.x * 256 + threadIdx.x;
    if (i >= N_NODES) return;
    int b = i >> 8, l = i & 255;
    unsigned c = 1;  // +1 self loop
#pragma unroll
    for (int s = 0; s < SEG; s++) c += pcnt[(size_t)(b * SEG + s) * 256 + l];
    float di = rsqrtf((float)c);
    dinv[i] = di;
    float2 xi = x[i];
    u[i] = make_float2(di * xi.x, di * xi.y);
}

__device__ __forceinline__ void agg_gather(const float2* __restrict__ table,
                                           const uint32x4 w, float2 v[4]) {
    v[0] = table[w[0] & 0x3FFFFu];
    v[1] = table[w[1] & 0x3FFFFu];
    v[2] = table[w[2] & 0x3FFFFu];
    v[3] = table[w[3] & 0x3FFFFu];
}

__device__ __forceinline__ void agg_accum(float* ax, float* ay,
                                          const uint32x4 w, const float2 v[4]) {
#pragma unroll
    for (int j = 0; j < 4; j++) {
        unsigned l = (w[j] >> 18) & 255u;
        atomicAdd(&ax[l], v[j].x);
        atomicAdd(&ay[l], v[j].y);
    }
}

// Partial aggregation: gather table[src] for one bucket-segment, LDS-sum,
// write a float2[256] partial.
__global__ __launch_bounds__(256) void agg_part_kernel(const unsigned* __restrict__ sorted,
                                                       const unsigned* __restrict__ bucketStart,
                                                       const float2* __restrict__ table,
                                                       float2* __restrict__ part) {
    __shared__ float ax[256], ay[256];
    int t = threadIdx.x;
    ax[t] = 0.f; ay[t] = 0.f;
    __syncthreads();
    int e0, e1;
    seg_bounds(bucketStart, blockIdx.x, e0, e1);

    int e0a = (e0 + 3) & ~3;
    if (e0a > e1) e0a = e1;
    if (t < e0a - e0) {
        unsigned w = sorted[e0 + t];
        float2 v = table[w & 0x3FFFFu];
        unsigned l = (w >> 18) & 255u;
        atomicAdd(&ax[l], v.x);
        atomicAdd(&ay[l], v.y);
    }
    int nq = (e1 - e0a) >> 2;
    const uint32x4* q4 = (const uint32x4*)(sorted + e0a);
    int q = t;
    for (; q + 768 < nq; q += 1024) {
        uint32x4 w0 = q4[q];
        uint32x4 w1 = q4[q + 256];
        uint32x4 w2 = q4[q + 512];
        uint32x4 w3 = q4[q + 768];
        float2 v0[4], v1[4], v2[4], v3[4];
        agg_gather(table, w0, v0);
        agg_gather(table, w1, v1);
        agg_gather(table, w2, v2);
        agg_gather(table, w3, v3);
        agg_accum(ax, ay, w0, v0);
        agg_accum(ax, ay, w1, v1);
        agg_accum(ax, ay, w2, v2);
        agg_accum(ax, ay, w3, v3);
    }
    for (; q < nq; q += 256) {
        uint32x4 w0 = q4[q];
        float2 v0[4];
        agg_gather(table, w0, v0);
        agg_accum(ax, ay, w0, v0);
    }
    int tail0 = e0a + (nq << 2);
    if (t < e1 - tail0) {
        unsigned w = sorted[tail0 + t];
        float2 v = table[w & 0x3FFFFu];
        unsigned l = (w >> 18) & 255u;
        atomicAdd(&ax[l], v.x);
        atomicAdd(&ay[l], v.y);
    }
    __syncthreads();
    part[(size_t)blockIdx.x * 256 + t] = make_float2(ax[t], ay[t]);
}

__global__ __launch_bounds__(256) void node2_kernel(const float2* __restrict__ u,
                                                    const float2* __restrict__ part,
                                                    const float* __restrict__ W1,
                                                    const float* __restrict__ b1,
                                                    const float* __restrict__ W2,
                                                    const float* __restrict__ dinv,
                                                    float2* __restrict__ g2) {
    int i = blockIdx.x * 256 + threadIdx.x;
    if (i >= N_NODES) return;
    int b = i >> 8, l = i & 255;
    float ax = 0.f, ay = 0.f;
#pragma unroll
    for (int s = 0; s < SEG; s++) {
        float2 p = part[(size_t)(b * SEG + s) * 256 + l];
        ax += p.x; ay += p.y;
    }
    float di = dinv[i];
    float2 uu = u[i];
    float c0 = di * (ax + uu.x);
    float c1 = di * (ay + uu.y);
    float a0 = 0.f, a1 = 0.f;
#pragma unroll
    for (int f = 0; f < 16; f++) {
        float o = fmaxf(c0 * W1[f] + c1 * W1[16 + f] + b1[f], 0.f);  // W1 (2,16)
        a0 += o * W2[2 * f];                                         // W2 (16,2)
        a1 += o * W2[2 * f + 1];
    }
    g2[i] = make_float2(di * a0, di * a1);
}

__global__ __launch_bounds__(256) void node3_kernel(const float2* __restrict__ g2,
                                                    const float2* __restrict__ part,
                                                    const float* __restrict__ b2,
                                                    const float* __restrict__ dinv,
                                                    float2* __restrict__ out) {
    int i = blockIdx.x * 256 + threadIdx.x;
    if (i >= N_NODES) return;
    int b = i >> 8, l = i & 255;
    float ax = 0.f, ay = 0.f;
#pragma unroll
    for (int s = 0; s < SEG; s++) {
        float2 p = part[(size_t)(b * SEG + s) * 256 + l];
        ax += p.x; ay += p.y;
    }
    float di = dinv[i];
    float2 g = g2[i];
    out[i] = make_float2(di * (ax + g.x) + b2[0],
                         di * (ay + g.y) + b2[1]);
}

// ---------------- fallback path (R2-style, needs only 8 MB ws) ----------------

__global__ __launch_bounds__(256) void fb_deg(const int* __restrict__ dst, int* __restrict__ degi) {
    int e = blockIdx.x * 256 + threadIdx.x;
    if (e < N_EDGES) atomicAdd(&degi[dst[e]], 1);
}
__global__ __launch_bounds__(256) void fb_node1(const float* __restrict__ x, const int* __restrict__ degi,
                                                float* __restrict__ dinv, float2* __restrict__ u) {
    int i = blockIdx.x * 256 + threadIdx.x;
    if (i >= N_NODES) return;
    float di = rsqrtf((float)(degi[i] + 1));
    dinv[i] = di;
    float2 xi = ((const float2*)x)[i];
    u[i] = make_float2(di * xi.x, di * xi.y);
}
__global__ __launch_bounds__(256) void fb_agg(const int* __restrict__ src, const int* __restrict__ dst,
                                              const float2* __restrict__ table, float* __restrict__ acc) {
    int e = blockIdx.x * 256 + threadIdx.x;
    if (e >= N_EDGES) return;
    float2 v = table[src[e]];
    size_t d = dst[e];
    unsafeAtomicAdd(&acc[2 * d], v.x);
    unsafeAtomicAdd(&acc[2 * d + 1], v.y);
}
__global__ __launch_bounds__(256) void fb_node2(const float2* __restrict__ u, const float2* __restrict__ A1,
                                                const float* __restrict__ W1, const float* __restrict__ b1,
                                                const float* __restrict__ W2, const float* __restrict__ dinv,
                                                float2* __restrict__ g2) {
    int i = blockIdx.x * 256 + threadIdx.x;
    if (i >= N_NODES) return;
    float di = dinv[i];
    float2 a = A1[i], uu = u[i];
    float c0 = di * (a.x + uu.x), c1 = di * (a.y + uu.y);
    float a0 = 0.f, a1 = 0.f;
#pragma unroll
    for (int f = 0; f < 16; f++) {
        float o = fmaxf(c0 * W1[f] + c1 * W1[16 + f] + b1[f], 0.f);
        a0 += o * W2[2 * f];
        a1 += o * W2[2 * f + 1];
    }
    g2[i] = make_float2(di * a0, di * a1);
}
__global__ __launch_bounds__(256) void fb_node3(const float2* __restrict__ g2, const float2* __restrict__ A2,
                                                const float* __restrict__ b2, const float* __restrict__ dinv,
                                                float2* __restrict__ out) {
    int i = blockIdx.x * 256 + threadIdx.x;
    if (i >= N_NODES) return;
    float di = dinv[i];
    float2 a = A2[i], g = g2[i];
    out[i] = make_float2(di * (a.x + g.x) + b2[0], di * (a.y + g.y) + b2[1]);
}

// ---------------- launcher ----------------

extern "C" void kernel_launch(void* const* d_in, const int* in_sizes, int n_in,
                              void* d_out, int out_size, void* d_ws, size_t ws_size,
                              hipStream_t stream) {
    const float* x  = (const float*)d_in[0];
    const float* W1 = (const float*)d_in[1];
    const float* b1 = (const float*)d_in[2];
    const float* W2 = (const float*)d_in[3];
    const float* b2 = (const float*)d_in[4];
    const int* ei   = (const int*)d_in[5];   // (2,E): row 0 = src, row 1 = dst
    const int* src = ei;
    const int* dst = ei + N_EDGES;
    float2* out = (float2*)d_out;

    // ws layout (4B words), same total as R5 (~61.6 MB):
    //   sorted      [E]                      12,800,000
    //   blockHist   [SORT_BLOCKS*K]           1,601,536  -- dead after scatter;
    //       reused for deg partials (3128*256 = 800,768 words) and
    //       agg partials (3128*512 = 1,601,536 words -- exact fit)
    //   bucketTotal [K]                             782
    //   bucketStart [K+1] (+1 pad)                  784
    //   dinv        [N]                         200,000
    //   u           [2N] (8B aligned)           400,000
    //   g2          [2N]                        400,000
    const size_t need = ((size_t)N_EDGES + (size_t)SORT_BLOCKS * K_BUCKETS + 782 + 784
                         + N_NODES + 2 * (size_t)N_NODES + 2 * (size_t)N_NODES) * 4;

    if (ws_size >= need) {
        unsigned* sorted      = (unsigned*)d_ws;
        unsigned* blockHist   = sorted + N_EDGES;
        unsigned* bucketTotal = blockHist + (size_t)SORT_BLOCKS * K_BUCKETS;
        unsigned* bucketStart = bucketTotal + 782;
        float*    dinv        = (float*)(bucketStart + 784);
        float2*   u           = (float2*)(dinv + N_NODES);
        float2*   g2          = u + N_NODES;
        unsigned* pcnt        = blockHist;            // deg partials (reuse)
        float2*   part        = (float2*)blockHist;   // agg partials (reuse)

        hist_kernel<<<SORT_BLOCKS, 256, 0, stream>>>(dst, blockHist);
        scan_perblock_kernel<<<K_BUCKETS, 256, 0, stream>>>(blockHist, bucketTotal);
        scan_buckets_kernel<<<1, 1024, 0, stream>>>(bucketTotal, bucketStart);
        scatter_kernel<<<SORT_BLOCKS, 256, 0, stream>>>(src, dst, blockHist, bucketTotal,
                                                        bucketStart, sorted);
        deg_part_kernel<<<K_BUCKETS * SEG, 256, 0, stream>>>(sorted, bucketStart, pcnt);
        node1_kernel<<<K_BUCKETS, 256, 0, stream>>>((const float2*)x, pcnt, dinv, u);
        agg_part_kernel<<<K_BUCKETS * SEG, 256, 0, stream>>>(sorted, bucketStart, u, part);
        node2_kernel<<<K_BUCKETS, 256, 0, stream>>>(u, part, W1, b1, W2, dinv, g2);
        agg_part_kernel<<<K_BUCKETS * SEG, 256, 0, stream>>>(sorted, bucketStart, g2, part);
        node3_kernel<<<K_BUCKETS, 256, 0, stream>>>(g2, part, b2, dinv, out);
    } else {
        // R2-style fallback (8 MB ws): global atomics, ~3.1 ms.
        float* ws = (float*)d_ws;
        int*   degi = (int*)ws;
        float* A1   = ws + N_NODES;
        float* A2   = A1 + 2 * (size_t)N_NODES;
        float* dinvF = A2 + 2 * (size_t)N_NODES;
        float2* uF  = (float2*)(dinvF + N_NODES);
        float2* g2F = uF + N_NODES;
        constexpr int EB = (N_EDGES + 255) / 256;
        constexpr int NB = (N_NODES + 255) / 256;
        (void)hipMemsetAsync(degi, 0, 5 * (size_t)N_NODES * sizeof(float), stream);
        fb_deg<<<EB, 256, 0, stream>>>(dst, degi);
        fb_node1<<<NB, 256, 0, stream>>>(x, degi, dinvF, uF);
        fb_agg<<<EB, 256, 0, stream>>>(src, dst, uF, A1);
        fb_node2<<<NB, 256, 0, stream>>>(uF, (const float2*)A1, W1, b1, W2, dinvF, g2F);
        fb_agg<<<EB, 256, 0, stream>>>(src, dst, g2F, A2);
        fb_node3<<<NB, 256, 0, stream>>>(g2F, (const float2*)A2, b2, dinvF, out);
    }
}